// Round 3
// baseline (1100.705 us; speedup 1.0000x reference)
//
#include <hip/hip_runtime.h>
#include <hip/hip_bf16.h>
#include <cstdint>
#include <cstddef>

// Problem constants
#define SEQ   2048
#define HID   2048
#define NH    32
#define NKVH  8
#define HD    64
#define KVDIM (NKVH * HD)   // 512

typedef __bf16 bf16_t;
typedef __bf16 bf16x8 __attribute__((ext_vector_type(8)));
typedef float  f32x4  __attribute__((ext_vector_type(4)));

// 8-element loaders -> bf16x8 (fp32 inputs get RTNE-converted; bf16 pass through)
__device__ __forceinline__ bf16x8 load8(const float* p) {
    const float4 lo = *(const float4*)p;
    const float4 hi = *(const float4*)(p + 4);
    bf16x8 r;
    r[0] = (bf16_t)lo.x; r[1] = (bf16_t)lo.y; r[2] = (bf16_t)lo.z; r[3] = (bf16_t)lo.w;
    r[4] = (bf16_t)hi.x; r[5] = (bf16_t)hi.y; r[6] = (bf16_t)hi.z; r[7] = (bf16_t)hi.w;
    return r;
}
__device__ __forceinline__ bf16x8 load8(const bf16_t* p) {
    return *(const bf16x8*)p;
}

// ---------------------------------------------------------------------------
// GEMM: C[M][N] = A[M][K] * B[N][K]^T   (fp32 accum, TC out)
// Tile 64x64, BK=32, 256 threads = 4 waves in 2x2; each wave: 2x2 of 16x16
// mfma_f32_16x16x32_bf16 tiles.
// Verified fragment layouts (learn_hip m89/m91):
//   A/B frag, lane l: row (l&15), 8 contiguous k at (l>>4)*8
//   C/D, lane l, reg r: col = l&15, row = (l>>4)*4 + r
// Requires M%64==0, N%64==0, K%32==0 (true here).
// ---------------------------------------------------------------------------
template <typename TA, typename TB, typename TC>
__global__ __launch_bounds__(256) void gemm_bt(const TA* __restrict__ A,
                                               const TB* __restrict__ B,
                                               TC* __restrict__ C,
                                               int M, int N, int K, int ldc)
{
    __shared__ alignas(16) bf16_t sa[64 * 32];
    __shared__ alignas(16) bf16_t sb[64 * 32];

    const int m0 = blockIdx.x * 64;
    const int n0 = blockIdx.y * 64;
    const int t = threadIdx.x;
    const int lane = t & 63;
    const int w = t >> 6;        // wave id 0..3
    const int wr = w >> 1;       // wave row 0..1 (32 rows each)
    const int wc = w & 1;        // wave col 0..1

    f32x4 acc[2][2] = {};

    // staging: thread t converts/loads one 8-elem chunk of A-tile and B-tile
    const int ar = t >> 2;           // row 0..63
    const int ac = (t & 3) * 8;      // k-col 0,8,16,24
    const TA* Ap = A + (size_t)(m0 + ar) * K + ac;
    const TB* Bp = B + (size_t)(n0 + ar) * K + ac;
    bf16_t* sap = &sa[ar * 32 + ac];
    bf16_t* sbp = &sb[ar * 32 + ac];

    const int q  = lane >> 4;    // quad 0..3
    const int mr = lane & 15;

    for (int k0 = 0; k0 < K; k0 += 32) {
        *(bf16x8*)sap = load8(Ap + k0);
        *(bf16x8*)sbp = load8(Bp + k0);
        __syncthreads();

#pragma unroll
        for (int i = 0; i < 2; ++i) {
            bf16x8 af = *(const bf16x8*)&sa[(wr * 32 + i * 16 + mr) * 32 + q * 8];
#pragma unroll
            for (int j = 0; j < 2; ++j) {
                bf16x8 bfr = *(const bf16x8*)&sb[(wc * 32 + j * 16 + mr) * 32 + q * 8];
                acc[i][j] = __builtin_amdgcn_mfma_f32_16x16x32_bf16(af, bfr, acc[i][j], 0, 0, 0);
            }
        }
        __syncthreads();
    }

    // epilogue
    const int cl = lane & 15;
#pragma unroll
    for (int i = 0; i < 2; ++i) {
#pragma unroll
        for (int j = 0; j < 2; ++j) {
            int row = m0 + wr * 32 + i * 16 + q * 4;
            int col = n0 + wc * 32 + j * 16 + cl;
#pragma unroll
            for (int r = 0; r < 4; ++r) {
                C[(size_t)(row + r) * ldc + col] = (TC)acc[i][j][r];
            }
        }
    }
}

// ---------------------------------------------------------------------------
// RoPE in-place on Q [SEQ][NH*HD] and K [SEQ][NKVH*HD], prefill positions.
// Pair (d, d+32) per thread, head dim 64 -> 32 pairs. Accurate powf/sincosf.
// ---------------------------------------------------------------------------
__global__ __launch_bounds__(256) void rope_kernel(bf16_t* __restrict__ Qm,
                                                   bf16_t* __restrict__ Km)
{
    int idx = blockIdx.x * blockDim.x + threadIdx.x;
    const int total = SEQ * (NH + NKVH) * 32;
    if (idx >= total) return;
    int d  = idx & 31;
    int hh = (idx >> 5) % (NH + NKVH);
    int s  = idx / (32 * (NH + NKVH));

    float inv = powf(10000.0f, -(float)d / 32.0f);  // theta^(-2d/64)
    float ang = (float)s * inv;
    float sn, cs;
    sincosf(ang, &sn, &cs);

    bf16_t* base;
    if (hh < NH) base = Qm + (size_t)s * (NH * HD) + hh * HD;
    else         base = Km + (size_t)s * KVDIM + (hh - NH) * HD;

    float x1 = (float)base[d];
    float x2 = (float)base[d + 32];
    base[d]      = (bf16_t)(x1 * cs - x2 * sn);
    base[d + 32] = (bf16_t)(x2 * cs + x1 * sn);
}

// ---------------------------------------------------------------------------
// Causal flash attention (scalar/VALU, fp32 math, bf16 workspace I/O).
// Grid: (SEQ/32, NH). One workgroup (256 thr) per (head, 32-query tile).
// K-blocks of 64 with online softmax. K staged transposed in LDS.
// Thread t owns score/output row r = t>>3 and 8 cols/dims (t&7)*8..+7.
// ---------------------------------------------------------------------------
__global__ __launch_bounds__(256) void attn_kernel(const bf16_t* __restrict__ Qm,
                                                   const bf16_t* __restrict__ Km,
                                                   const bf16_t* __restrict__ Vm,
                                                   bf16_t* __restrict__ Om)
{
    const int h   = blockIdx.y;
    const int q0  = blockIdx.x * 32;
    const int kvh = h >> 2;          // H/KVH = 4
    const int t   = threadIdx.x;

    __shared__ float qs[32][64];   // pre-scaled Q tile
    __shared__ float kt[64][64];   // K transposed: [d][c]
    __shared__ float vs[64][64];   // V natural:    [c][d]
    __shared__ float ps[32][64];   // probabilities
    __shared__ float red[32][8];
    __shared__ float mrow[32], lrow[32], arow[32];

    const float scale = 0.125f;    // 1/sqrt(64)

    // load Q tile (fp32, pre-scaled)
    {
        int r = t >> 3, d = (t & 7) * 8;
        const bf16_t* qp = Qm + (size_t)(q0 + r) * (NH * HD) + h * HD + d;
#pragma unroll
        for (int j = 0; j < 8; ++j) qs[r][d + j] = (float)qp[j] * scale;
    }
    if (t < 32) { mrow[t] = -1e30f; lrow[t] = 0.0f; }

    float o[8] = {0.f, 0.f, 0.f, 0.f, 0.f, 0.f, 0.f, 0.f};
    const int rr = t >> 3;
    const int cb = (t & 7) * 8;
    const int qmax = q0 + 31;

    for (int k0 = 0; k0 <= qmax; k0 += 64) {
        // stage K (transposed) and V blocks, bf16 -> fp32
        {
            int row = t & 63;
            int c0b = (t >> 6) * 8;
#pragma unroll
            for (int half = 0; half < 2; ++half) {
                int c0 = c0b + half * 32;
                const bf16_t* kp = Km + (size_t)(k0 + row) * KVDIM + kvh * HD + c0;
                const bf16_t* vp = Vm + (size_t)(k0 + row) * KVDIM + kvh * HD + c0;
#pragma unroll
                for (int j = 0; j < 8; ++j) {
                    kt[c0 + j][row] = (float)kp[j];
                    vs[row][c0 + j] = (float)vp[j];
                }
            }
        }
        __syncthreads();

        // scores: row rr, cols cb..cb+7
        float sc[8];
#pragma unroll
        for (int j = 0; j < 8; ++j) sc[j] = 0.0f;
        for (int d = 0; d < 64; ++d) {
            float qv = qs[rr][d];
#pragma unroll
            for (int j = 0; j < 8; ++j) sc[j] += qv * kt[d][cb + j];
        }
        // causal mask + local max
        float mloc = -1e30f;
#pragma unroll
        for (int j = 0; j < 8; ++j) {
            if (k0 + cb + j > q0 + rr) sc[j] = -1e30f;
            mloc = fmaxf(mloc, sc[j]);
        }
        red[rr][t & 7] = mloc;
        __syncthreads();

        if (t < 32) {
            float m = mrow[t];
            float mx = m;
#pragma unroll
            for (int j = 0; j < 8; ++j) mx = fmaxf(mx, red[t][j]);
            float al = (m <= -1e30f) ? 0.0f : __expf(m - mx);
            mrow[t] = mx;
            arow[t] = al;
        }
        __syncthreads();

        float mx = mrow[rr];
        float lsum = 0.0f;
#pragma unroll
        for (int j = 0; j < 8; ++j) {
            float p = __expf(sc[j] - mx);
            ps[rr][cb + j] = p;
            lsum += p;
        }
        red[rr][t & 7] = lsum;
        __syncthreads();

        if (t < 32) {
            float ssum = 0.0f;
#pragma unroll
            for (int j = 0; j < 8; ++j) ssum += red[t][j];
            lrow[t] = lrow[t] * arow[t] + ssum;
        }

        // O update: row rr, dims cb..cb+7
        float alpha = arow[rr];
#pragma unroll
        for (int j = 0; j < 8; ++j) o[j] *= alpha;
        for (int c = 0; c < 64; ++c) {
            float pv = ps[rr][c];
#pragma unroll
            for (int j = 0; j < 8; ++j) o[j] += pv * vs[c][cb + j];
        }
        __syncthreads();
    }

    float linv = 1.0f / lrow[rr];
    bf16_t* op = Om + (size_t)(q0 + rr) * (NH * HD) + h * HD + cb;
#pragma unroll
    for (int j = 0; j < 8; ++j) op[j] = (bf16_t)(o[j] * linv);
}

// ---------------------------------------------------------------------------
extern "C" void kernel_launch(void* const* d_in, const int* in_sizes, int n_in,
                              void* d_out, int out_size, void* d_ws, size_t ws_size,
                              hipStream_t stream)
{
    // Reference dtypes: all inputs float32; output float32.
    const float* X  = (const float*)d_in[0];
    const float* Wq = (const float*)d_in[1];
    const float* Wk = (const float*)d_in[2];
    const float* Wv = (const float*)d_in[3];
    const float* Wo = (const float*)d_in[4];
    float* out = (float*)d_out;

    bf16_t* Qb = (bf16_t*)d_ws;                       // [SEQ][NH*HD]   8 MB
    bf16_t* Kb = Qb + (size_t)SEQ * (NH * HD);        // [SEQ][KVDIM]   2 MB
    bf16_t* Vb = Kb + (size_t)SEQ * KVDIM;            // [SEQ][KVDIM]   2 MB
    bf16_t* Ob = Vb + (size_t)SEQ * KVDIM;            // [SEQ][NH*HD]   8 MB

    dim3 blk(256);

    // QKV projections (fp32 in -> bf16 out)
    gemm_bt<float, float, bf16_t><<<dim3(SEQ / 64, (NH * HD) / 64), blk, 0, stream>>>(X, Wq, Qb, SEQ, NH * HD, HID, NH * HD);
    gemm_bt<float, float, bf16_t><<<dim3(SEQ / 64, KVDIM / 64),     blk, 0, stream>>>(X, Wk, Kb, SEQ, KVDIM, HID, KVDIM);
    gemm_bt<float, float, bf16_t><<<dim3(SEQ / 64, KVDIM / 64),     blk, 0, stream>>>(X, Wv, Vb, SEQ, KVDIM, HID, KVDIM);

    // RoPE (in place on Q, K)
    {
        int total = SEQ * (NH + NKVH) * 32;
        rope_kernel<<<(total + 255) / 256, 256, 0, stream>>>(Qb, Kb);
    }

    // causal GQA attention
    attn_kernel<<<dim3(SEQ / 32, NH), blk, 0, stream>>>(Qb, Kb, Vb, Ob);

    // output projection -> d_out (bf16 A, fp32 B, fp32 out)
    gemm_bt<bf16_t, float, float><<<dim3(SEQ / 64, HID / 64), blk, 0, stream>>>(Ob, Wo, out, SEQ, HID, NH * HD, HID);
}

// Round 4
// 434.938 us; speedup vs baseline: 2.5307x; 2.5307x over previous
//
#include <hip/hip_runtime.h>
#include <hip/hip_bf16.h>
#include <cstdint>
#include <cstddef>

// Problem constants
#define SEQ   2048
#define HID   2048
#define NH    32
#define NKVH  8
#define HD    64
#define KVDIM (NKVH * HD)   // 512

typedef __bf16 bf16_t;
typedef __bf16 bf16x8 __attribute__((ext_vector_type(8)));
typedef float  f32x4  __attribute__((ext_vector_type(4)));

// 8-element loaders -> bf16x8 (fp32 inputs get RTNE-converted; bf16 pass through)
__device__ __forceinline__ bf16x8 load8(const float* p) {
    const float4 lo = *(const float4*)p;
    const float4 hi = *(const float4*)(p + 4);
    bf16x8 r;
    r[0] = (bf16_t)lo.x; r[1] = (bf16_t)lo.y; r[2] = (bf16_t)lo.z; r[3] = (bf16_t)lo.w;
    r[4] = (bf16_t)hi.x; r[5] = (bf16_t)hi.y; r[6] = (bf16_t)hi.z; r[7] = (bf16_t)hi.w;
    return r;
}
__device__ __forceinline__ bf16x8 load8(const bf16_t* p) {
    return *(const bf16x8*)p;
}

// ---------------------------------------------------------------------------
// GEMM: C[M][N] = A[M][K] * B[N][K]^T   (fp32 accum, TC out)
// Tile 64x64, BK=32, 256 threads = 4 waves in 2x2; each wave: 2x2 of 16x16
// mfma_f32_16x16x32_bf16 tiles.
// Verified fragment layouts (learn_hip m89/m91):
//   A/B frag, lane l: row (l&15), 8 contiguous k at (l>>4)*8
//   C/D, lane l, reg r: col = l&15, row = (l>>4)*4 + r
// TRANSC: store C transposed (Ct[n][m], ldc = leading dim of Ct = M);
// per-lane the 4 acc values land contiguous (Ct[col][row..row+3]).
// ---------------------------------------------------------------------------
template <typename TA, typename TB, typename TC, bool TRANSC>
__global__ __launch_bounds__(256) void gemm_bt(const TA* __restrict__ A,
                                               const TB* __restrict__ B,
                                               TC* __restrict__ C,
                                               int M, int N, int K, int ldc)
{
    __shared__ alignas(16) bf16_t sa[64 * 32];
    __shared__ alignas(16) bf16_t sb[64 * 32];

    const int m0 = blockIdx.x * 64;
    const int n0 = blockIdx.y * 64;
    const int t = threadIdx.x;
    const int lane = t & 63;
    const int w = t >> 6;        // wave id 0..3
    const int wr = w >> 1;       // wave row 0..1 (32 rows each)
    const int wc = w & 1;        // wave col 0..1

    f32x4 acc[2][2] = {};

    const int ar = t >> 2;           // row 0..63
    const int ac = (t & 3) * 8;      // k-col 0,8,16,24
    const TA* Ap = A + (size_t)(m0 + ar) * K + ac;
    const TB* Bp = B + (size_t)(n0 + ar) * K + ac;
    bf16_t* sap = &sa[ar * 32 + ac];
    bf16_t* sbp = &sb[ar * 32 + ac];

    const int q  = lane >> 4;    // quad 0..3
    const int mr = lane & 15;

    for (int k0 = 0; k0 < K; k0 += 32) {
        *(bf16x8*)sap = load8(Ap + k0);
        *(bf16x8*)sbp = load8(Bp + k0);
        __syncthreads();

#pragma unroll
        for (int i = 0; i < 2; ++i) {
            bf16x8 af = *(const bf16x8*)&sa[(wr * 32 + i * 16 + mr) * 32 + q * 8];
#pragma unroll
            for (int j = 0; j < 2; ++j) {
                bf16x8 bfr = *(const bf16x8*)&sb[(wc * 32 + j * 16 + mr) * 32 + q * 8];
                acc[i][j] = __builtin_amdgcn_mfma_f32_16x16x32_bf16(af, bfr, acc[i][j], 0, 0, 0);
            }
        }
        __syncthreads();
    }

    const int cl = lane & 15;
#pragma unroll
    for (int i = 0; i < 2; ++i) {
#pragma unroll
        for (int j = 0; j < 2; ++j) {
            int row = m0 + wr * 32 + i * 16 + q * 4;
            int col = n0 + wc * 32 + j * 16 + cl;
#pragma unroll
            for (int r = 0; r < 4; ++r) {
                if (TRANSC)
                    C[(size_t)col * ldc + row + r] = (TC)acc[i][j][r];
                else
                    C[(size_t)(row + r) * ldc + col] = (TC)acc[i][j][r];
            }
        }
    }
}

// ---------------------------------------------------------------------------
// RoPE in-place on Q [SEQ][NH*HD] and K [SEQ][NKVH*HD], prefill positions.
// ---------------------------------------------------------------------------
__global__ __launch_bounds__(256) void rope_kernel(bf16_t* __restrict__ Qm,
                                                   bf16_t* __restrict__ Km)
{
    int idx = blockIdx.x * blockDim.x + threadIdx.x;
    const int total = SEQ * (NH + NKVH) * 32;
    if (idx >= total) return;
    int d  = idx & 31;
    int hh = (idx >> 5) % (NH + NKVH);
    int s  = idx / (32 * (NH + NKVH));

    // theta^(-2d/64) = exp2(-d * log2(10000)/32)
    float inv = exp2f(-(float)d * 0.4152410118609203f);
    float ang = (float)s * inv;
    float sn, cs;
    sincosf(ang, &sn, &cs);

    bf16_t* base;
    if (hh < NH) base = Qm + (size_t)s * (NH * HD) + hh * HD;
    else         base = Km + (size_t)s * KVDIM + (hh - NH) * HD;

    float x1 = (float)base[d];
    float x2 = (float)base[d + 32];
    base[d]      = (bf16_t)(x1 * cs - x2 * sn);
    base[d + 32] = (bf16_t)(x2 * cs + x1 * sn);
}

// ---------------------------------------------------------------------------
// MFMA causal flash attention.
// Grid: (SEQ/64, NH); 256 threads = 4 waves; wave w owns q rows q0+w*16..+15.
// K staged natural ks[n][d]; V staged from pre-transposed Vt as vs[d][c].
// QK^T: D = mfma(qfrag, kfrag)  -> S[row=q, col=n] in C-layout.
// Online softmax per row held in registers (rows = (lane>>4)*4+r, matching
// the C-layout row mapping, so alpha-rescale of the O accumulator is direct).
// P goes C-layout -> LDS -> A-layout (verified m120 pattern), then
// PV: D = mfma(pfrag, vfrag) -> O[row=q, col=d].
// ---------------------------------------------------------------------------
__global__ __launch_bounds__(256) void attn_mfma(const bf16_t* __restrict__ Qm,
                                                 const bf16_t* __restrict__ Km,
                                                 const bf16_t* __restrict__ Vt,
                                                 bf16_t* __restrict__ Om)
{
    const int h   = blockIdx.y;
    const int q0  = blockIdx.x * 64;
    const int kvh = h >> 2;            // H/KVH = 4
    const int t   = threadIdx.x;
    const int w   = t >> 6;            // wave 0..3
    const int lane = t & 63;
    const int n16 = lane & 15;
    const int q4  = lane >> 4;         // quad 0..3

    __shared__ alignas(16) bf16_t ks[64][72];      // K natural [n][d]
    __shared__ alignas(16) bf16_t vs[64][72];      // V transposed [d][c]
    __shared__ alignas(16) bf16_t psm[4][16][72];  // per-wave P scratch [m][c]

    // persistent Q fragments (A-layout), loaded once from global
    const int qrow = q0 + w * 16 + n16;
    const bf16_t* qbase = Qm + (size_t)qrow * HID + h * HD;
    const bf16x8 qf0 = *(const bf16x8*)(qbase + q4 * 8);
    const bf16x8 qf1 = *(const bf16x8*)(qbase + 32 + q4 * 8);

    f32x4 acc[4] = {};                 // O accumulator, 4 d-tiles
    float m_i[4], l_i[4];
#pragma unroll
    for (int r = 0; r < 4; ++r) { m_i[r] = -1e30f; l_i[r] = 0.0f; }

    // staging indices: thread t loads row t>>2, chunks (t&3)*8 and +32
    const int srow = t >> 2;
    const int sc0  = (t & 3) * 8;
    const bf16_t* kgbase  = Km + (size_t)kvh * HD + sc0;
    const bf16_t* vgbase  = Vt + (size_t)(kvh * HD + srow) * SEQ + sc0;

    const float scale = 0.125f;        // 1/sqrt(64)
    const int rowg0 = q0 + w * 16 + q4 * 4;
    const int nblocks = q0 / 64 + 1;

    for (int kb = 0; kb < nblocks; ++kb) {
        const int k0 = kb * 64;
        // ---- stage K (natural) and V (transposed) tiles ----
        {
            const bf16_t* kp = kgbase + (size_t)(k0 + srow) * KVDIM;
            *(bf16x8*)&ks[srow][sc0]      = *(const bf16x8*)(kp);
            *(bf16x8*)&ks[srow][sc0 + 32] = *(const bf16x8*)(kp + 32);
            const bf16_t* vp = vgbase + k0;
            *(bf16x8*)&vs[srow][sc0]      = *(const bf16x8*)(vp);
            *(bf16x8*)&vs[srow][sc0 + 32] = *(const bf16x8*)(vp + 32);
        }
        __syncthreads();

        // ---- S = Q K^T (4 col-tiles of 16) ----
        f32x4 st[4];
#pragma unroll
        for (int jt = 0; jt < 4; ++jt) {
            bf16x8 kf0 = *(const bf16x8*)&ks[jt * 16 + n16][q4 * 8];
            bf16x8 kf1 = *(const bf16x8*)&ks[jt * 16 + n16][32 + q4 * 8];
            f32x4 s = {};
            s = __builtin_amdgcn_mfma_f32_16x16x32_bf16(qf0, kf0, s, 0, 0, 0);
            s = __builtin_amdgcn_mfma_f32_16x16x32_bf16(qf1, kf1, s, 0, 0, 0);
            st[jt] = s;
        }

        // ---- scale + causal mask ----
#pragma unroll
        for (int jt = 0; jt < 4; ++jt) {
            int colg = k0 + jt * 16 + n16;
#pragma unroll
            for (int r = 0; r < 4; ++r) {
                float v = st[jt][r] * scale;
                st[jt][r] = (colg > rowg0 + r) ? -1e30f : v;
            }
        }

        // ---- online softmax (row = rowg0 + r, reduce across 16 lanes) ----
        float rmax[4];
#pragma unroll
        for (int r = 0; r < 4; ++r)
            rmax[r] = fmaxf(fmaxf(st[0][r], st[1][r]), fmaxf(st[2][r], st[3][r]));
#pragma unroll
        for (int msk = 1; msk < 16; msk <<= 1)
#pragma unroll
            for (int r = 0; r < 4; ++r)
                rmax[r] = fmaxf(rmax[r], __shfl_xor(rmax[r], msk));

        float alpha[4];
#pragma unroll
        for (int r = 0; r < 4; ++r) {
            float mn = fmaxf(m_i[r], rmax[r]);
            alpha[r] = __expf(m_i[r] - mn);
            m_i[r] = mn;
        }

        float rsum[4] = {0.f, 0.f, 0.f, 0.f};
#pragma unroll
        for (int jt = 0; jt < 4; ++jt)
#pragma unroll
            for (int r = 0; r < 4; ++r) {
                float p = __expf(st[jt][r] - m_i[r]);
                st[jt][r] = p;
                rsum[r] += p;
            }
#pragma unroll
        for (int msk = 1; msk < 16; msk <<= 1)
#pragma unroll
            for (int r = 0; r < 4; ++r)
                rsum[r] += __shfl_xor(rsum[r], msk);

#pragma unroll
        for (int r = 0; r < 4; ++r)
            l_i[r] = l_i[r] * alpha[r] + rsum[r];
#pragma unroll
        for (int jd = 0; jd < 4; ++jd)
#pragma unroll
            for (int r = 0; r < 4; ++r)
                acc[jd][r] *= alpha[r];

        // ---- P: C-layout regs -> per-wave LDS (bf16) ----
#pragma unroll
        for (int jt = 0; jt < 4; ++jt)
#pragma unroll
            for (int r = 0; r < 4; ++r)
                psm[w][q4 * 4 + r][jt * 16 + n16] = (bf16_t)st[jt][r];
        // (same-wave read-after-write; lgkmcnt handled by compiler)

        // ---- O += P V (4 d-tiles) ----
        bf16x8 pf0 = *(const bf16x8*)&psm[w][n16][q4 * 8];
        bf16x8 pf1 = *(const bf16x8*)&psm[w][n16][32 + q4 * 8];
#pragma unroll
        for (int jd = 0; jd < 4; ++jd) {
            bf16x8 vf0 = *(const bf16x8*)&vs[jd * 16 + n16][q4 * 8];
            bf16x8 vf1 = *(const bf16x8*)&vs[jd * 16 + n16][32 + q4 * 8];
            acc[jd] = __builtin_amdgcn_mfma_f32_16x16x32_bf16(pf0, vf0, acc[jd], 0, 0, 0);
            acc[jd] = __builtin_amdgcn_mfma_f32_16x16x32_bf16(pf1, vf1, acc[jd], 0, 0, 0);
        }
        __syncthreads();   // ks/vs reused next block
    }

    // ---- epilogue: O / l ----
    float linv[4];
#pragma unroll
    for (int r = 0; r < 4; ++r) linv[r] = 1.0f / l_i[r];
#pragma unroll
    for (int jd = 0; jd < 4; ++jd)
#pragma unroll
        for (int r = 0; r < 4; ++r) {
            int rowg = rowg0 + r;
            Om[(size_t)rowg * HID + h * HD + jd * 16 + n16] = (bf16_t)(acc[jd][r] * linv[r]);
        }
}

// ---------------------------------------------------------------------------
extern "C" void kernel_launch(void* const* d_in, const int* in_sizes, int n_in,
                              void* d_out, int out_size, void* d_ws, size_t ws_size,
                              hipStream_t stream)
{
    const float* X  = (const float*)d_in[0];
    const float* Wq = (const float*)d_in[1];
    const float* Wk = (const float*)d_in[2];
    const float* Wv = (const float*)d_in[3];
    const float* Wo = (const float*)d_in[4];
    float* out = (float*)d_out;

    bf16_t* Qb = (bf16_t*)d_ws;                       // [SEQ][NH*HD]   8 MB
    bf16_t* Kb = Qb + (size_t)SEQ * (NH * HD);        // [SEQ][KVDIM]   2 MB
    bf16_t* Vt = Kb + (size_t)SEQ * KVDIM;            // [KVDIM][SEQ]   2 MB (transposed)
    bf16_t* Ob = Vt + (size_t)SEQ * KVDIM;            // [SEQ][NH*HD]   8 MB

    dim3 blk(256);

    // QKV projections (fp32 in -> bf16 out); V written transposed
    gemm_bt<float, float, bf16_t, false><<<dim3(SEQ / 64, (NH * HD) / 64), blk, 0, stream>>>(X, Wq, Qb, SEQ, NH * HD, HID, NH * HD);
    gemm_bt<float, float, bf16_t, false><<<dim3(SEQ / 64, KVDIM / 64),     blk, 0, stream>>>(X, Wk, Kb, SEQ, KVDIM, HID, KVDIM);
    gemm_bt<float, float, bf16_t, true ><<<dim3(SEQ / 64, KVDIM / 64),     blk, 0, stream>>>(X, Wv, Vt, SEQ, KVDIM, HID, SEQ);

    // RoPE (in place on Q, K)
    {
        int total = SEQ * (NH + NKVH) * 32;
        rope_kernel<<<(total + 255) / 256, 256, 0, stream>>>(Qb, Kb);
    }

    // causal GQA attention (MFMA flash)
    attn_mfma<<<dim3(SEQ / 64, NH), blk, 0, stream>>>(Qb, Kb, Vt, Ob);

    // output projection -> d_out (bf16 A, fp32 B, fp32 out)
    gemm_bt<bf16_t, float, float, false><<<dim3(SEQ / 64, HID / 64), blk, 0, stream>>>(Ob, Wo, out, SEQ, HID, NH * HD, HID);
}

// Round 5
// 411.037 us; speedup vs baseline: 2.6779x; 1.0581x over previous
//
#include <hip/hip_runtime.h>
#include <hip/hip_bf16.h>
#include <cstdint>
#include <cstddef>

// Problem constants
#define SEQ   2048
#define HID   2048
#define NH    32
#define NKVH  8
#define HD    64
#define KVDIM (NKVH * HD)   // 512

typedef __bf16 bf16_t;
typedef __bf16 bf16x8 __attribute__((ext_vector_type(8)));
typedef float  f32x4  __attribute__((ext_vector_type(4)));

// log2(10000)/32  (RoPE: theta^(-d/32) = exp2(-d*L))
#define ROPE_L 0.4152410118609203f

__device__ __forceinline__ bf16x8 load8(const float* p) {
    const float4 lo = *(const float4*)p;
    const float4 hi = *(const float4*)(p + 4);
    bf16x8 r;
    r[0] = (bf16_t)lo.x; r[1] = (bf16_t)lo.y; r[2] = (bf16_t)lo.z; r[3] = (bf16_t)lo.w;
    r[4] = (bf16_t)hi.x; r[5] = (bf16_t)hi.y; r[6] = (bf16_t)hi.z; r[7] = (bf16_t)hi.w;
    return r;
}
__device__ __forceinline__ bf16x8 load8(const bf16_t* p) {
    return *(const bf16x8*)p;
}

// ---------------------------------------------------------------------------
// 128x128-tile GEMM core (m93 structure): 256 thr = 4 waves 2x2, each wave a
// 64x64 quadrant = 4x4 mfma_f32_16x16x32_bf16 tiles, BK=32.
// Fragment layouts (HW-verified m89/m91): A/B lane l -> row l&15, k (l>>4)*8;
// C/D lane l reg r -> col l&15, row (l>>4)*4+r.
// Per-wave-iter: 16 MFMA + 8 ds_read_b128 (m97 histogram shape).
// ---------------------------------------------------------------------------
#define GEMM128_PROLOG()                                                      \
    __shared__ alignas(16) bf16_t sa[128 * 32];                               \
    __shared__ alignas(16) bf16_t sb[128 * 32];                               \
    const int t = threadIdx.x;                                                \
    const int lane = t & 63;                                                  \
    const int w  = t >> 6;                                                    \
    const int wr = w >> 1;                                                    \
    const int wc = w & 1;                                                     \
    const int n16 = lane & 15;                                                \
    const int q4  = lane >> 4;                                                \
    f32x4 acc[4][4] = {};                                                     \
    const int srow = t >> 1;          /* 0..127 */                            \
    const int scol = (t & 1) * 16;    /* 0 or 16 */

#define GEMM128_KLOOP(Aptr, Bptr, Kdim)                                       \
    {                                                                         \
        bf16_t* sap = &sa[srow * 32 + scol];                                  \
        bf16_t* sbp = &sb[srow * 32 + scol];                                  \
        for (int k0 = 0; k0 < (Kdim); k0 += 32) {                             \
            *(bf16x8*)sap       = load8((Aptr) + k0);                         \
            *(bf16x8*)(sap + 8) = load8((Aptr) + k0 + 8);                     \
            *(bf16x8*)sbp       = load8((Bptr) + k0);                         \
            *(bf16x8*)(sbp + 8) = load8((Bptr) + k0 + 8);                     \
            __syncthreads();                                                  \
            bf16x8 bfrag[4];                                                  \
            _Pragma("unroll")                                                 \
            for (int j = 0; j < 4; ++j)                                       \
                bfrag[j] = *(const bf16x8*)&sb[(wc * 64 + j * 16 + n16) * 32 + q4 * 8]; \
            _Pragma("unroll")                                                 \
            for (int i = 0; i < 4; ++i) {                                     \
                bf16x8 af = *(const bf16x8*)&sa[(wr * 64 + i * 16 + n16) * 32 + q4 * 8]; \
                _Pragma("unroll")                                             \
                for (int j = 0; j < 4; ++j)                                   \
                    acc[i][j] = __builtin_amdgcn_mfma_f32_16x16x32_bf16(af, bfrag[j], acc[i][j], 0, 0, 0); \
            }                                                                 \
            __syncthreads();                                                  \
        }                                                                     \
    }

// ---------------------------------------------------------------------------
// Fused QKV projection + RoPE.  A = X fp32 [SEQ][HID].
// Grid (SEQ/128, 3072/128): col-blocks 0..15 -> Q, 16..19 -> K, 20..23 -> V.
// RoPE applied in registers (pair halves live in col-tiles jt and jt+2 of the
// same lane since wave col-span 64 == head dim). V written transposed
// [KVDIM][SEQ] for the attention kernel's vs[d][c] staging.
// ---------------------------------------------------------------------------
__global__ __launch_bounds__(256) void qkv_gemm(const float* __restrict__ X,
                                                const float* __restrict__ Wq,
                                                const float* __restrict__ Wk,
                                                const float* __restrict__ Wv,
                                                bf16_t* __restrict__ Qb,
                                                bf16_t* __restrict__ Kb,
                                                bf16_t* __restrict__ Vt)
{
    const int m0 = blockIdx.x * 128;
    const int n0 = blockIdx.y * 128;

    const float* B;
    int mode, nc;
    if (n0 < NH * HD)            { B = Wq + (size_t)n0 * HID;                mode = 0; nc = n0; }
    else if (n0 < NH * HD + KVDIM) { B = Wk + (size_t)(n0 - NH * HD) * HID;  mode = 1; nc = n0 - NH * HD; }
    else                         { B = Wv + (size_t)(n0 - NH * HD - KVDIM) * HID; mode = 2; nc = n0 - NH * HD - KVDIM; }

    GEMM128_PROLOG()

    const float* Ap = X + (size_t)(m0 + srow) * HID + scol;
    const float* Bp = B + (size_t)srow * HID + scol;
    GEMM128_KLOOP(Ap, Bp, HID)

    if (mode < 2) {
        // ---- RoPE in registers: d = jt*16+n16 (jt<2), partner at jt+2 ----
#pragma unroll
        for (int jt = 0; jt < 2; ++jt) {
            float dd = (float)(jt * 16 + n16);
            float inv = exp2f(-dd * ROPE_L);
#pragma unroll
            for (int i = 0; i < 4; ++i) {
#pragma unroll
                for (int r = 0; r < 4; ++r) {
                    int pos = m0 + wr * 64 + i * 16 + q4 * 4 + r;
                    float ang = (float)pos * inv;
                    float sn, cs;
                    sincosf(ang, &sn, &cs);
                    float x1 = acc[i][jt][r], x2 = acc[i][jt + 2][r];
                    acc[i][jt][r]     = x1 * cs - x2 * sn;
                    acc[i][jt + 2][r] = x2 * cs + x1 * sn;
                }
            }
        }
        bf16_t* dst = (mode == 0) ? Qb : Kb;
        const int ld = (mode == 0) ? NH * HD : KVDIM;
#pragma unroll
        for (int i = 0; i < 4; ++i)
#pragma unroll
            for (int j = 0; j < 4; ++j) {
                int row = m0 + wr * 64 + i * 16 + q4 * 4;
                int col = nc + wc * 64 + j * 16 + n16;
#pragma unroll
                for (int r = 0; r < 4; ++r)
                    dst[(size_t)(row + r) * ld + col] = (bf16_t)acc[i][j][r];
            }
    } else {
        // ---- V: store transposed, 4 consecutive rows per lane contiguous ----
#pragma unroll
        for (int i = 0; i < 4; ++i)
#pragma unroll
            for (int j = 0; j < 4; ++j) {
                int row = m0 + wr * 64 + i * 16 + q4 * 4;
                int col = nc + wc * 64 + j * 16 + n16;
#pragma unroll
                for (int r = 0; r < 4; ++r)
                    Vt[(size_t)col * SEQ + row + r] = (bf16_t)acc[i][j][r];
            }
    }
}

// ---------------------------------------------------------------------------
// O projection: out[SEQ][HID] fp32 = Ob[SEQ][HID](bf16) * Wo[HID][HID]^T(fp32)
// ---------------------------------------------------------------------------
__global__ __launch_bounds__(256) void o_gemm(const bf16_t* __restrict__ A,
                                              const float* __restrict__ Bw,
                                              float* __restrict__ C)
{
    const int m0 = blockIdx.x * 128;
    const int n0 = blockIdx.y * 128;

    GEMM128_PROLOG()

    const bf16_t* Ap = A + (size_t)(m0 + srow) * HID + scol;
    const float*  Bp = Bw + (size_t)(n0 + srow) * HID + scol;
    GEMM128_KLOOP(Ap, Bp, HID)

#pragma unroll
    for (int i = 0; i < 4; ++i)
#pragma unroll
        for (int j = 0; j < 4; ++j) {
            int row = m0 + wr * 64 + i * 16 + q4 * 4;
            int col = n0 + wc * 64 + j * 16 + n16;
#pragma unroll
            for (int r = 0; r < 4; ++r)
                C[(size_t)(row + r) * HID + col] = acc[i][j][r];
        }
}

// ---------------------------------------------------------------------------
// MFMA causal flash attention.  1D grid, heads fastest, HEAVIEST q-tiles
// dispatched first (load-balance: work per block = q0/64+1 k-iterations).
// ---------------------------------------------------------------------------
__global__ __launch_bounds__(256) void attn_mfma(const bf16_t* __restrict__ Qm,
                                                 const bf16_t* __restrict__ Km,
                                                 const bf16_t* __restrict__ Vt,
                                                 bf16_t* __restrict__ Om)
{
    const int h   = blockIdx.x & (NH - 1);
    const int qt  = (SEQ / 64 - 1) - (blockIdx.x >> 5);   // heavy first
    const int q0  = qt * 64;
    const int kvh = h >> 2;            // H/KVH = 4
    const int t   = threadIdx.x;
    const int w   = t >> 6;
    const int lane = t & 63;
    const int n16 = lane & 15;
    const int q4  = lane >> 4;

    __shared__ alignas(16) bf16_t ks[64][72];      // K natural [n][d]
    __shared__ alignas(16) bf16_t vs[64][72];      // V transposed [d][c]
    __shared__ alignas(16) bf16_t psm[4][16][72];  // per-wave P scratch [m][c]

    const int qrow = q0 + w * 16 + n16;
    const bf16_t* qbase = Qm + (size_t)qrow * HID + h * HD;
    const bf16x8 qf0 = *(const bf16x8*)(qbase + q4 * 8);
    const bf16x8 qf1 = *(const bf16x8*)(qbase + 32 + q4 * 8);

    f32x4 acc[4] = {};
    float m_i[4], l_i[4];
#pragma unroll
    for (int r = 0; r < 4; ++r) { m_i[r] = -1e30f; l_i[r] = 0.0f; }

    const int srow = t >> 2;
    const int sc0  = (t & 3) * 8;
    const bf16_t* kgbase = Km + (size_t)kvh * HD + sc0;
    const bf16_t* vgbase = Vt + (size_t)(kvh * HD + srow) * SEQ + sc0;

    const float scale = 0.125f;
    const int rowg0 = q0 + w * 16 + q4 * 4;
    const int nblocks = q0 / 64 + 1;

    for (int kb = 0; kb < nblocks; ++kb) {
        const int k0 = kb * 64;
        {
            const bf16_t* kp = kgbase + (size_t)(k0 + srow) * KVDIM;
            *(bf16x8*)&ks[srow][sc0]      = *(const bf16x8*)(kp);
            *(bf16x8*)&ks[srow][sc0 + 32] = *(const bf16x8*)(kp + 32);
            const bf16_t* vp = vgbase + k0;
            *(bf16x8*)&vs[srow][sc0]      = *(const bf16x8*)(vp);
            *(bf16x8*)&vs[srow][sc0 + 32] = *(const bf16x8*)(vp + 32);
        }
        __syncthreads();

        f32x4 st[4];
#pragma unroll
        for (int jt = 0; jt < 4; ++jt) {
            bf16x8 kf0 = *(const bf16x8*)&ks[jt * 16 + n16][q4 * 8];
            bf16x8 kf1 = *(const bf16x8*)&ks[jt * 16 + n16][32 + q4 * 8];
            f32x4 s = {};
            s = __builtin_amdgcn_mfma_f32_16x16x32_bf16(qf0, kf0, s, 0, 0, 0);
            s = __builtin_amdgcn_mfma_f32_16x16x32_bf16(qf1, kf1, s, 0, 0, 0);
            st[jt] = s;
        }

#pragma unroll
        for (int jt = 0; jt < 4; ++jt) {
            int colg = k0 + jt * 16 + n16;
#pragma unroll
            for (int r = 0; r < 4; ++r) {
                float v = st[jt][r] * scale;
                st[jt][r] = (colg > rowg0 + r) ? -1e30f : v;
            }
        }

        float rmax[4];
#pragma unroll
        for (int r = 0; r < 4; ++r)
            rmax[r] = fmaxf(fmaxf(st[0][r], st[1][r]), fmaxf(st[2][r], st[3][r]));
#pragma unroll
        for (int msk = 1; msk < 16; msk <<= 1)
#pragma unroll
            for (int r = 0; r < 4; ++r)
                rmax[r] = fmaxf(rmax[r], __shfl_xor(rmax[r], msk));

        float alpha[4];
#pragma unroll
        for (int r = 0; r < 4; ++r) {
            float mn = fmaxf(m_i[r], rmax[r]);
            alpha[r] = __expf(m_i[r] - mn);
            m_i[r] = mn;
        }

        float rsum[4] = {0.f, 0.f, 0.f, 0.f};
#pragma unroll
        for (int jt = 0; jt < 4; ++jt)
#pragma unroll
            for (int r = 0; r < 4; ++r) {
                float p = __expf(st[jt][r] - m_i[r]);
                st[jt][r] = p;
                rsum[r] += p;
            }
#pragma unroll
        for (int msk = 1; msk < 16; msk <<= 1)
#pragma unroll
            for (int r = 0; r < 4; ++r)
                rsum[r] += __shfl_xor(rsum[r], msk);

#pragma unroll
        for (int r = 0; r < 4; ++r)
            l_i[r] = l_i[r] * alpha[r] + rsum[r];
#pragma unroll
        for (int jd = 0; jd < 4; ++jd)
#pragma unroll
            for (int r = 0; r < 4; ++r)
                acc[jd][r] *= alpha[r];

#pragma unroll
        for (int jt = 0; jt < 4; ++jt)
#pragma unroll
            for (int r = 0; r < 4; ++r)
                psm[w][q4 * 4 + r][jt * 16 + n16] = (bf16_t)st[jt][r];

        bf16x8 pf0 = *(const bf16x8*)&psm[w][n16][q4 * 8];
        bf16x8 pf1 = *(const bf16x8*)&psm[w][n16][32 + q4 * 8];
#pragma unroll
        for (int jd = 0; jd < 4; ++jd) {
            bf16x8 vf0 = *(const bf16x8*)&vs[jd * 16 + n16][q4 * 8];
            bf16x8 vf1 = *(const bf16x8*)&vs[jd * 16 + n16][32 + q4 * 8];
            acc[jd] = __builtin_amdgcn_mfma_f32_16x16x32_bf16(pf0, vf0, acc[jd], 0, 0, 0);
            acc[jd] = __builtin_amdgcn_mfma_f32_16x16x32_bf16(pf1, vf1, acc[jd], 0, 0, 0);
        }
        __syncthreads();
    }

    float linv[4];
#pragma unroll
    for (int r = 0; r < 4; ++r) linv[r] = 1.0f / l_i[r];
#pragma unroll
    for (int jd = 0; jd < 4; ++jd)
#pragma unroll
        for (int r = 0; r < 4; ++r) {
            int rowg = rowg0 + r;
            Om[(size_t)rowg * HID + h * HD + jd * 16 + n16] = (bf16_t)(acc[jd][r] * linv[r]);
        }
}

// ---------------------------------------------------------------------------
extern "C" void kernel_launch(void* const* d_in, const int* in_sizes, int n_in,
                              void* d_out, int out_size, void* d_ws, size_t ws_size,
                              hipStream_t stream)
{
    const float* X  = (const float*)d_in[0];
    const float* Wq = (const float*)d_in[1];
    const float* Wk = (const float*)d_in[2];
    const float* Wv = (const float*)d_in[3];
    const float* Wo = (const float*)d_in[4];
    float* out = (float*)d_out;

    bf16_t* Qb = (bf16_t*)d_ws;                       // [SEQ][NH*HD]   8 MB
    bf16_t* Kb = Qb + (size_t)SEQ * (NH * HD);        // [SEQ][KVDIM]   2 MB
    bf16_t* Vt = Kb + (size_t)SEQ * KVDIM;            // [KVDIM][SEQ]   2 MB (transposed)
    bf16_t* Ob = Vt + (size_t)SEQ * KVDIM;            // [SEQ][NH*HD]   8 MB

    dim3 blk(256);

    // fused QKV projection + RoPE (V transposed)
    qkv_gemm<<<dim3(SEQ / 128, (NH * HD + 2 * KVDIM) / 128), blk, 0, stream>>>(X, Wq, Wk, Wv, Qb, Kb, Vt);

    // causal GQA attention (MFMA flash, heavy-first ordering)
    attn_mfma<<<dim3((SEQ / 64) * NH), blk, 0, stream>>>(Qb, Kb, Vt, Ob);

    // output projection -> d_out
    o_gemm<<<dim3(SEQ / 128, HID / 128), blk, 0, stream>>>(Ob, Wo, out);
}

// Round 6
// 294.505 us; speedup vs baseline: 3.7375x; 1.3957x over previous
//
#include <hip/hip_runtime.h>
#include <hip/hip_bf16.h>
#include <cstdint>
#include <cstddef>

// Problem constants
#define SEQ   2048
#define HID   2048
#define NH    32
#define NKVH  8
#define HD    64
#define KVDIM (NKVH * HD)   // 512

typedef __bf16 bf16_t;
typedef __bf16 bf16x8 __attribute__((ext_vector_type(8)));
typedef float  f32x4  __attribute__((ext_vector_type(4)));

// log2(10000)/32  (RoPE: theta^(-d/32) = exp2(-d*L))
#define ROPE_L 0.4152410118609203f

__device__ __forceinline__ bf16x8 load8(const float* p) {
    const float4 lo = *(const float4*)p;
    const float4 hi = *(const float4*)(p + 4);
    bf16x8 r;
    r[0] = (bf16_t)lo.x; r[1] = (bf16_t)lo.y; r[2] = (bf16_t)lo.z; r[3] = (bf16_t)lo.w;
    r[4] = (bf16_t)hi.x; r[5] = (bf16_t)hi.y; r[6] = (bf16_t)hi.z; r[7] = (bf16_t)hi.w;
    return r;
}

// async global->LDS, 16B per lane; LDS dest = wave-uniform base + lane*16
__device__ __forceinline__ void load_lds16(const bf16_t* g, bf16_t* l) {
    __builtin_amdgcn_global_load_lds((const __attribute__((address_space(1))) void*)g,
                                     (__attribute__((address_space(3))) void*)l,
                                     16, 0, 0);
}

// ---------------------------------------------------------------------------
// One-shot fp32 -> bf16 conversion of all GEMM operands (X, Wq, Wk, Wv, Wo).
// 8 elems/thread, wave-uniform buffer select (1M-elem boundaries).
// ---------------------------------------------------------------------------
#define NX  (SEQ * HID)          // 4M
#define NWQ (NH * HD * HID)      // 4M
#define NWK (KVDIM * HID)        // 1M
#define NWV (KVDIM * HID)        // 1M
#define NWO (HID * NH * HD)      // 4M
#define NTOT (NX + NWQ + NWK + NWV + NWO)   // 14M

__global__ __launch_bounds__(256) void cvt_all(const float* __restrict__ X,
                                               const float* __restrict__ Wq,
                                               const float* __restrict__ Wk,
                                               const float* __restrict__ Wv,
                                               const float* __restrict__ Wo,
                                               bf16_t* __restrict__ Xb,
                                               bf16_t* __restrict__ Wqb,
                                               bf16_t* __restrict__ Wkb,
                                               bf16_t* __restrict__ Wvb,
                                               bf16_t* __restrict__ Wob)
{
    size_t i = ((size_t)blockIdx.x * 256 + threadIdx.x) * 8;
    if (i >= NTOT) return;
    const size_t E0 = NX, E1 = E0 + NWQ, E2 = E1 + NWK, E3 = E2 + NWV;
    const float* s; bf16_t* d; size_t off;
    if (i < E0)      { s = X;  d = Xb;  off = i; }
    else if (i < E1) { s = Wq; d = Wqb; off = i - E0; }
    else if (i < E2) { s = Wk; d = Wkb; off = i - E1; }
    else if (i < E3) { s = Wv; d = Wvb; off = i - E2; }
    else             { s = Wo; d = Wob; off = i - E3; }
    *(bf16x8*)(d + off) = load8(s + off);
}

// ---------------------------------------------------------------------------
// 128x128-tile bf16 GEMM core (m97 structure): 256 thr = 4 waves 2x2, each
// wave a 64x64 quadrant = 4x4 mfma_f32_16x16x32_bf16 tiles, BK=32.
// Staging via global_load_lds width=16: per wave 2 A-insts + 2 B-insts per
// K-iter (16 rows x 32 k each, lane l -> row l>>2, bytes (l&3)*16).
// Fragment layouts (HW-verified m89/m91): A/B lane l -> row l&15, k (l>>4)*8;
// C/D lane l reg r -> col l&15, row (l>>4)*4+r.
// ---------------------------------------------------------------------------
#define GEMM128_PROLOG()                                                      \
    __shared__ alignas(16) bf16_t sa[128 * 32];                               \
    __shared__ alignas(16) bf16_t sb[128 * 32];                               \
    const int t = threadIdx.x;                                                \
    const int lane = t & 63;                                                  \
    const int w  = t >> 6;                                                    \
    const int wr = w >> 1;                                                    \
    const int wc = w & 1;                                                     \
    const int n16 = lane & 15;                                                \
    const int q4  = lane >> 4;                                                \
    f32x4 acc[4][4] = {};

// Abase/Bbase must already point at tile row 0 (A + m0*K, B + n0*K)
#define GEMM128_KLOOP(Abase, Bbase, Kdim)                                     \
    {                                                                         \
        const int lrow = w * 32 + (lane >> 2);                                \
        const int lcol = (lane & 3) * 8;                                      \
        const bf16_t* ag = (Abase) + (size_t)lrow * (Kdim) + lcol;            \
        const bf16_t* bg = (Bbase) + (size_t)lrow * (Kdim) + lcol;            \
        bf16_t* la0 = &sa[(w * 32) * 32];                                     \
        bf16_t* la1 = &sa[(w * 32 + 16) * 32];                                \
        bf16_t* lb0 = &sb[(w * 32) * 32];                                     \
        bf16_t* lb1 = &sb[(w * 32 + 16) * 32];                                \
        for (int k0 = 0; k0 < (Kdim); k0 += 32) {                             \
            load_lds16(ag + k0, la0);                                         \
            load_lds16(ag + k0 + (size_t)16 * (Kdim), la1);                   \
            load_lds16(bg + k0, lb0);                                         \
            load_lds16(bg + k0 + (size_t)16 * (Kdim), lb1);                   \
            __syncthreads();                                                  \
            bf16x8 bfrag[4];                                                  \
            _Pragma("unroll")                                                 \
            for (int j = 0; j < 4; ++j)                                       \
                bfrag[j] = *(const bf16x8*)&sb[(wc * 64 + j * 16 + n16) * 32 + q4 * 8]; \
            _Pragma("unroll")                                                 \
            for (int i = 0; i < 4; ++i) {                                     \
                bf16x8 af = *(const bf16x8*)&sa[(wr * 64 + i * 16 + n16) * 32 + q4 * 8]; \
                _Pragma("unroll")                                             \
                for (int j = 0; j < 4; ++j)                                   \
                    acc[i][j] = __builtin_amdgcn_mfma_f32_16x16x32_bf16(af, bfrag[j], acc[i][j], 0, 0, 0); \
            }                                                                 \
            __syncthreads();                                                  \
        }                                                                     \
    }

// ---------------------------------------------------------------------------
// Fused QKV projection + RoPE (all-bf16 operands).
// Grid (SEQ/128, 3072/128): col-blocks 0..15 -> Q, 16..19 -> K, 20..23 -> V.
// RoPE applied in registers (pair halves in col-tiles jt and jt+2).
// V written transposed [KVDIM][SEQ].
// ---------------------------------------------------------------------------
__global__ __launch_bounds__(256) void qkv_gemm(const bf16_t* __restrict__ Xb,
                                                const bf16_t* __restrict__ Wqb,
                                                const bf16_t* __restrict__ Wkb,
                                                const bf16_t* __restrict__ Wvb,
                                                bf16_t* __restrict__ Qb,
                                                bf16_t* __restrict__ Kb,
                                                bf16_t* __restrict__ Vt)
{
    const int m0 = blockIdx.x * 128;
    const int n0 = blockIdx.y * 128;

    const bf16_t* B;
    int mode, nc;
    if (n0 < NH * HD)              { B = Wqb + (size_t)n0 * HID;                    mode = 0; nc = n0; }
    else if (n0 < NH * HD + KVDIM) { B = Wkb + (size_t)(n0 - NH * HD) * HID;        mode = 1; nc = n0 - NH * HD; }
    else                           { B = Wvb + (size_t)(n0 - NH * HD - KVDIM) * HID; mode = 2; nc = n0 - NH * HD - KVDIM; }

    GEMM128_PROLOG()
    GEMM128_KLOOP(Xb + (size_t)m0 * HID, B, HID)

    if (mode < 2) {
        // ---- RoPE in registers: d = jt*16+n16 (jt<2), partner at jt+2 ----
#pragma unroll
        for (int jt = 0; jt < 2; ++jt) {
            float dd = (float)(jt * 16 + n16);
            float inv = exp2f(-dd * ROPE_L);
#pragma unroll
            for (int i = 0; i < 4; ++i) {
#pragma unroll
                for (int r = 0; r < 4; ++r) {
                    int pos = m0 + wr * 64 + i * 16 + q4 * 4 + r;
                    float ang = (float)pos * inv;
                    float sn, cs;
                    sincosf(ang, &sn, &cs);
                    float x1 = acc[i][jt][r], x2 = acc[i][jt + 2][r];
                    acc[i][jt][r]     = x1 * cs - x2 * sn;
                    acc[i][jt + 2][r] = x2 * cs + x1 * sn;
                }
            }
        }
        bf16_t* dst = (mode == 0) ? Qb : Kb;
        const int ld = (mode == 0) ? NH * HD : KVDIM;
#pragma unroll
        for (int i = 0; i < 4; ++i)
#pragma unroll
            for (int j = 0; j < 4; ++j) {
                int row = m0 + wr * 64 + i * 16 + q4 * 4;
                int col = nc + wc * 64 + j * 16 + n16;
#pragma unroll
                for (int r = 0; r < 4; ++r)
                    dst[(size_t)(row + r) * ld + col] = (bf16_t)acc[i][j][r];
            }
    } else {
        // ---- V: store transposed, 4 consecutive rows per lane contiguous ----
#pragma unroll
        for (int i = 0; i < 4; ++i)
#pragma unroll
            for (int j = 0; j < 4; ++j) {
                int row = m0 + wr * 64 + i * 16 + q4 * 4;
                int col = nc + wc * 64 + j * 16 + n16;
#pragma unroll
                for (int r = 0; r < 4; ++r)
                    Vt[(size_t)col * SEQ + row + r] = (bf16_t)acc[i][j][r];
            }
    }
}

// ---------------------------------------------------------------------------
// O projection: out[SEQ][HID] fp32 = Ob[SEQ][HID](bf16) * Wob[HID][HID]^T(bf16)
// ---------------------------------------------------------------------------
__global__ __launch_bounds__(256) void o_gemm(const bf16_t* __restrict__ A,
                                              const bf16_t* __restrict__ Bw,
                                              float* __restrict__ C)
{
    const int m0 = blockIdx.x * 128;
    const int n0 = blockIdx.y * 128;

    GEMM128_PROLOG()
    GEMM128_KLOOP(A + (size_t)m0 * HID, Bw + (size_t)n0 * HID, HID)

#pragma unroll
    for (int i = 0; i < 4; ++i)
#pragma unroll
        for (int j = 0; j < 4; ++j) {
            int row = m0 + wr * 64 + i * 16 + q4 * 4;
            int col = n0 + wc * 64 + j * 16 + n16;
#pragma unroll
            for (int r = 0; r < 4; ++r)
                C[(size_t)(row + r) * HID + col] = acc[i][j][r];
        }
}

// ---------------------------------------------------------------------------
// MFMA causal flash attention.  1D grid, heads fastest, heaviest q-tiles
// dispatched first (work per block = q0/64+1 k-iterations).
// ---------------------------------------------------------------------------
__global__ __launch_bounds__(256) void attn_mfma(const bf16_t* __restrict__ Qm,
                                                 const bf16_t* __restrict__ Km,
                                                 const bf16_t* __restrict__ Vt,
                                                 bf16_t* __restrict__ Om)
{
    const int h   = blockIdx.x & (NH - 1);
    const int qt  = (SEQ / 64 - 1) - (blockIdx.x >> 5);   // heavy first
    const int q0  = qt * 64;
    const int kvh = h >> 2;            // H/KVH = 4
    const int t   = threadIdx.x;
    const int w   = t >> 6;
    const int lane = t & 63;
    const int n16 = lane & 15;
    const int q4  = lane >> 4;

    __shared__ alignas(16) bf16_t ks[64][72];      // K natural [n][d]
    __shared__ alignas(16) bf16_t vs[64][72];      // V transposed [d][c]
    __shared__ alignas(16) bf16_t psm[4][16][72];  // per-wave P scratch [m][c]

    const int qrow = q0 + w * 16 + n16;
    const bf16_t* qbase = Qm + (size_t)qrow * HID + h * HD;
    const bf16x8 qf0 = *(const bf16x8*)(qbase + q4 * 8);
    const bf16x8 qf1 = *(const bf16x8*)(qbase + 32 + q4 * 8);

    f32x4 acc[4] = {};
    float m_i[4], l_i[4];
#pragma unroll
    for (int r = 0; r < 4; ++r) { m_i[r] = -1e30f; l_i[r] = 0.0f; }

    const int srow = t >> 2;
    const int sc0  = (t & 3) * 8;
    const bf16_t* kgbase = Km + (size_t)kvh * HD + sc0;
    const bf16_t* vgbase = Vt + (size_t)(kvh * HD + srow) * SEQ + sc0;

    const float scale = 0.125f;
    const int rowg0 = q0 + w * 16 + q4 * 4;
    const int nblocks = q0 / 64 + 1;

    for (int kb = 0; kb < nblocks; ++kb) {
        const int k0 = kb * 64;
        {
            const bf16_t* kp = kgbase + (size_t)(k0 + srow) * KVDIM;
            *(bf16x8*)&ks[srow][sc0]      = *(const bf16x8*)(kp);
            *(bf16x8*)&ks[srow][sc0 + 32] = *(const bf16x8*)(kp + 32);
            const bf16_t* vp = vgbase + k0;
            *(bf16x8*)&vs[srow][sc0]      = *(const bf16x8*)(vp);
            *(bf16x8*)&vs[srow][sc0 + 32] = *(const bf16x8*)(vp + 32);
        }
        __syncthreads();

        f32x4 st[4];
#pragma unroll
        for (int jt = 0; jt < 4; ++jt) {
            bf16x8 kf0 = *(const bf16x8*)&ks[jt * 16 + n16][q4 * 8];
            bf16x8 kf1 = *(const bf16x8*)&ks[jt * 16 + n16][32 + q4 * 8];
            f32x4 s = {};
            s = __builtin_amdgcn_mfma_f32_16x16x32_bf16(qf0, kf0, s, 0, 0, 0);
            s = __builtin_amdgcn_mfma_f32_16x16x32_bf16(qf1, kf1, s, 0, 0, 0);
            st[jt] = s;
        }

#pragma unroll
        for (int jt = 0; jt < 4; ++jt) {
            int colg = k0 + jt * 16 + n16;
#pragma unroll
            for (int r = 0; r < 4; ++r) {
                float v = st[jt][r] * scale;
                st[jt][r] = (colg > rowg0 + r) ? -1e30f : v;
            }
        }

        float rmax[4];
#pragma unroll
        for (int r = 0; r < 4; ++r)
            rmax[r] = fmaxf(fmaxf(st[0][r], st[1][r]), fmaxf(st[2][r], st[3][r]));
#pragma unroll
        for (int msk = 1; msk < 16; msk <<= 1)
#pragma unroll
            for (int r = 0; r < 4; ++r)
                rmax[r] = fmaxf(rmax[r], __shfl_xor(rmax[r], msk));

        float alpha[4];
#pragma unroll
        for (int r = 0; r < 4; ++r) {
            float mn = fmaxf(m_i[r], rmax[r]);
            alpha[r] = __expf(m_i[r] - mn);
            m_i[r] = mn;
        }

        float rsum[4] = {0.f, 0.f, 0.f, 0.f};
#pragma unroll
        for (int jt = 0; jt < 4; ++jt)
#pragma unroll
            for (int r = 0; r < 4; ++r) {
                float p = __expf(st[jt][r] - m_i[r]);
                st[jt][r] = p;
                rsum[r] += p;
            }
#pragma unroll
        for (int msk = 1; msk < 16; msk <<= 1)
#pragma unroll
            for (int r = 0; r < 4; ++r)
                rsum[r] += __shfl_xor(rsum[r], msk);

#pragma unroll
        for (int r = 0; r < 4; ++r)
            l_i[r] = l_i[r] * alpha[r] + rsum[r];
#pragma unroll
        for (int jd = 0; jd < 4; ++jd)
#pragma unroll
            for (int r = 0; r < 4; ++r)
                acc[jd][r] *= alpha[r];

#pragma unroll
        for (int jt = 0; jt < 4; ++jt)
#pragma unroll
            for (int r = 0; r < 4; ++r)
                psm[w][q4 * 4 + r][jt * 16 + n16] = (bf16_t)st[jt][r];

        bf16x8 pf0 = *(const bf16x8*)&psm[w][n16][q4 * 8];
        bf16x8 pf1 = *(const bf16x8*)&psm[w][n16][32 + q4 * 8];
#pragma unroll
        for (int jd = 0; jd < 4; ++jd) {
            bf16x8 vf0 = *(const bf16x8*)&vs[jd * 16 + n16][q4 * 8];
            bf16x8 vf1 = *(const bf16x8*)&vs[jd * 16 + n16][32 + q4 * 8];
            acc[jd] = __builtin_amdgcn_mfma_f32_16x16x32_bf16(pf0, vf0, acc[jd], 0, 0, 0);
            acc[jd] = __builtin_amdgcn_mfma_f32_16x16x32_bf16(pf1, vf1, acc[jd], 0, 0, 0);
        }
        __syncthreads();
    }

    float linv[4];
#pragma unroll
    for (int r = 0; r < 4; ++r) linv[r] = 1.0f / l_i[r];
#pragma unroll
    for (int jd = 0; jd < 4; ++jd)
#pragma unroll
        for (int r = 0; r < 4; ++r) {
            int rowg = rowg0 + r;
            Om[(size_t)rowg * HID + h * HD + jd * 16 + n16] = (bf16_t)(acc[jd][r] * linv[r]);
        }
}

// ---------------------------------------------------------------------------
extern "C" void kernel_launch(void* const* d_in, const int* in_sizes, int n_in,
                              void* d_out, int out_size, void* d_ws, size_t ws_size,
                              hipStream_t stream)
{
    const float* X  = (const float*)d_in[0];
    const float* Wq = (const float*)d_in[1];
    const float* Wk = (const float*)d_in[2];
    const float* Wv = (const float*)d_in[3];
    const float* Wo = (const float*)d_in[4];
    float* out = (float*)d_out;

    bf16_t* Xb  = (bf16_t*)d_ws;                      // [SEQ][HID]     8 MB
    bf16_t* Wqb = Xb  + (size_t)NX;                   // [2048][2048]   8 MB
    bf16_t* Wkb = Wqb + (size_t)NWQ;                  // [512][2048]    2 MB
    bf16_t* Wvb = Wkb + (size_t)NWK;                  // [512][2048]    2 MB
    bf16_t* Wob = Wvb + (size_t)NWV;                  // [2048][2048]   8 MB
    bf16_t* Qb  = Wob + (size_t)NWO;                  // [SEQ][NH*HD]   8 MB
    bf16_t* Kb  = Qb  + (size_t)SEQ * (NH * HD);      // [SEQ][KVDIM]   2 MB
    bf16_t* Vt  = Kb  + (size_t)SEQ * KVDIM;          // [KVDIM][SEQ]   2 MB
    bf16_t* Ob  = Vt  + (size_t)SEQ * KVDIM;          // [SEQ][NH*HD]   8 MB

    dim3 blk(256);

    // one-shot fp32 -> bf16 conversion of all operands
    cvt_all<<<dim3((NTOT / 8 + 255) / 256), blk, 0, stream>>>(X, Wq, Wk, Wv, Wo, Xb, Wqb, Wkb, Wvb, Wob);

    // fused QKV projection + RoPE (V transposed)
    qkv_gemm<<<dim3(SEQ / 128, (NH * HD + 2 * KVDIM) / 128), blk, 0, stream>>>(Xb, Wqb, Wkb, Wvb, Qb, Kb, Vt);

    // causal GQA attention (MFMA flash, heavy-first ordering)
    attn_mfma<<<dim3((SEQ / 64) * NH), blk, 0, stream>>>(Qb, Kb, Vt, Ob);

    // output projection -> d_out
    o_gemm<<<dim3(SEQ / 128, HID / 128), blk, 0, stream>>>(Ob, Wob, out);
}

// Round 7
// 292.779 us; speedup vs baseline: 3.7595x; 1.0059x over previous
//
#include <hip/hip_runtime.h>
#include <hip/hip_bf16.h>
#include <cstdint>
#include <cstddef>

// Problem constants
#define SEQ   2048
#define HID   2048
#define NH    32
#define NKVH  8
#define HD    64
#define KVDIM (NKVH * HD)   // 512

typedef __bf16 bf16_t;
typedef __bf16 bf16x8 __attribute__((ext_vector_type(8)));
typedef float  f32x4  __attribute__((ext_vector_type(4)));

// log2(10000)/32  (RoPE: theta^(-d/32) = exp2(-d*L))
#define ROPE_L 0.4152410118609203f

__device__ __forceinline__ bf16x8 load8(const float* p) {
    const float4 lo = *(const float4*)p;
    const float4 hi = *(const float4*)(p + 4);
    bf16x8 r;
    r[0] = (bf16_t)lo.x; r[1] = (bf16_t)lo.y; r[2] = (bf16_t)lo.z; r[3] = (bf16_t)lo.w;
    r[4] = (bf16_t)hi.x; r[5] = (bf16_t)hi.y; r[6] = (bf16_t)hi.z; r[7] = (bf16_t)hi.w;
    return r;
}

// async global->LDS, 16B per lane; LDS dest = wave-uniform base + lane*16
__device__ __forceinline__ void load_lds16(const bf16_t* g, bf16_t* l) {
    __builtin_amdgcn_global_load_lds((const __attribute__((address_space(1))) void*)g,
                                     (__attribute__((address_space(3))) void*)l,
                                     16, 0, 0);
}

// ---------------------------------------------------------------------------
// One-shot fp32 -> bf16 conversion of all GEMM operands (X, Wq, Wk, Wv, Wo).
// ---------------------------------------------------------------------------
#define NX  (SEQ * HID)          // 4M
#define NWQ (NH * HD * HID)      // 4M
#define NWK (KVDIM * HID)        // 1M
#define NWV (KVDIM * HID)        // 1M
#define NWO (HID * NH * HD)      // 4M
#define NTOT (NX + NWQ + NWK + NWV + NWO)   // 14M

__global__ __launch_bounds__(256) void cvt_all(const float* __restrict__ X,
                                               const float* __restrict__ Wq,
                                               const float* __restrict__ Wk,
                                               const float* __restrict__ Wv,
                                               const float* __restrict__ Wo,
                                               bf16_t* __restrict__ Xb,
                                               bf16_t* __restrict__ Wqb,
                                               bf16_t* __restrict__ Wkb,
                                               bf16_t* __restrict__ Wvb,
                                               bf16_t* __restrict__ Wob)
{
    size_t i = ((size_t)blockIdx.x * 256 + threadIdx.x) * 8;
    if (i >= NTOT) return;
    const size_t E0 = NX, E1 = E0 + NWQ, E2 = E1 + NWK, E3 = E2 + NWV;
    const float* s; bf16_t* d; size_t off;
    if (i < E0)      { s = X;  d = Xb;  off = i; }
    else if (i < E1) { s = Wq; d = Wqb; off = i - E0; }
    else if (i < E2) { s = Wk; d = Wkb; off = i - E1; }
    else if (i < E3) { s = Wv; d = Wvb; off = i - E2; }
    else             { s = Wo; d = Wob; off = i - E3; }
    *(bf16x8*)(d + off) = load8(s + off);
}

// ---------------------------------------------------------------------------
// 128x128-tile bf16 GEMM core (m97 structure): 256 thr = 4 waves 2x2, each
// wave a 64x64 quadrant = 4x4 mfma_f32_16x16x32_bf16 tiles, BK=32.
// Staging via global_load_lds width=16.
// Fragment layouts (HW-verified m89/m91): A/B lane l -> row l&15, k (l>>4)*8;
// C/D lane l reg r -> col l&15, row (l>>4)*4+r.
// ---------------------------------------------------------------------------
#define GEMM128_PROLOG()                                                      \
    __shared__ alignas(16) bf16_t sa[128 * 32];                               \
    __shared__ alignas(16) bf16_t sb[128 * 32];                               \
    const int t = threadIdx.x;                                                \
    const int lane = t & 63;                                                  \
    const int w  = t >> 6;                                                    \
    const int wr = w >> 1;                                                    \
    const int wc = w & 1;                                                     \
    const int n16 = lane & 15;                                                \
    const int q4  = lane >> 4;                                                \
    f32x4 acc[4][4] = {};

#define GEMM128_KLOOP(Abase, Bbase, Kdim)                                     \
    {                                                                         \
        const int lrow = w * 32 + (lane >> 2);                                \
        const int lcol = (lane & 3) * 8;                                      \
        const bf16_t* ag = (Abase) + (size_t)lrow * (Kdim) + lcol;            \
        const bf16_t* bg = (Bbase) + (size_t)lrow * (Kdim) + lcol;            \
        bf16_t* la0 = &sa[(w * 32) * 32];                                     \
        bf16_t* la1 = &sa[(w * 32 + 16) * 32];                                \
        bf16_t* lb0 = &sb[(w * 32) * 32];                                     \
        bf16_t* lb1 = &sb[(w * 32 + 16) * 32];                                \
        for (int k0 = 0; k0 < (Kdim); k0 += 32) {                             \
            load_lds16(ag + k0, la0);                                         \
            load_lds16(ag + k0 + (size_t)16 * (Kdim), la1);                   \
            load_lds16(bg + k0, lb0);                                         \
            load_lds16(bg + k0 + (size_t)16 * (Kdim), lb1);                   \
            __syncthreads();                                                  \
            bf16x8 bfrag[4];                                                  \
            _Pragma("unroll")                                                 \
            for (int j = 0; j < 4; ++j)                                       \
                bfrag[j] = *(const bf16x8*)&sb[(wc * 64 + j * 16 + n16) * 32 + q4 * 8]; \
            _Pragma("unroll")                                                 \
            for (int i = 0; i < 4; ++i) {                                     \
                bf16x8 af = *(const bf16x8*)&sa[(wr * 64 + i * 16 + n16) * 32 + q4 * 8]; \
                _Pragma("unroll")                                             \
                for (int j = 0; j < 4; ++j)                                   \
                    acc[i][j] = __builtin_amdgcn_mfma_f32_16x16x32_bf16(af, bfrag[j], acc[i][j], 0, 0, 0); \
            }                                                                 \
            __syncthreads();                                                  \
        }                                                                     \
    }

// ---------------------------------------------------------------------------
// Fused QKV projection + RoPE (all-bf16 operands).
// Grid (SEQ/128, 3072/128): col-blocks 0..15 -> Q, 16..19 -> K, 20..23 -> V.
// Q is additionally PRE-SCALED by 1/8 (= 1/sqrt(HD), exact in bf16) so the
// attention kernel's QK^T needs no scale multiply.
// V written transposed [KVDIM][SEQ].
// ---------------------------------------------------------------------------
__global__ __launch_bounds__(256) void qkv_gemm(const bf16_t* __restrict__ Xb,
                                                const bf16_t* __restrict__ Wqb,
                                                const bf16_t* __restrict__ Wkb,
                                                const bf16_t* __restrict__ Wvb,
                                                bf16_t* __restrict__ Qb,
                                                bf16_t* __restrict__ Kb,
                                                bf16_t* __restrict__ Vt)
{
    const int m0 = blockIdx.x * 128;
    const int n0 = blockIdx.y * 128;

    const bf16_t* B;
    int mode, nc;
    if (n0 < NH * HD)              { B = Wqb + (size_t)n0 * HID;                    mode = 0; nc = n0; }
    else if (n0 < NH * HD + KVDIM) { B = Wkb + (size_t)(n0 - NH * HD) * HID;        mode = 1; nc = n0 - NH * HD; }
    else                           { B = Wvb + (size_t)(n0 - NH * HD - KVDIM) * HID; mode = 2; nc = n0 - NH * HD - KVDIM; }

    GEMM128_PROLOG()
    GEMM128_KLOOP(Xb + (size_t)m0 * HID, B, HID)

    if (mode < 2) {
        // ---- RoPE in registers: d = jt*16+n16 (jt<2), partner at jt+2 ----
#pragma unroll
        for (int jt = 0; jt < 2; ++jt) {
            float dd = (float)(jt * 16 + n16);
            float inv = exp2f(-dd * ROPE_L);
#pragma unroll
            for (int i = 0; i < 4; ++i) {
#pragma unroll
                for (int r = 0; r < 4; ++r) {
                    int pos = m0 + wr * 64 + i * 16 + q4 * 4 + r;
                    float ang = (float)pos * inv;
                    float sn, cs;
                    sincosf(ang, &sn, &cs);
                    float x1 = acc[i][jt][r], x2 = acc[i][jt + 2][r];
                    acc[i][jt][r]     = x1 * cs - x2 * sn;
                    acc[i][jt + 2][r] = x2 * cs + x1 * sn;
                }
            }
        }
        const float osc = (mode == 0) ? 0.125f : 1.0f;   // pre-scale Q by 1/sqrt(HD)
        bf16_t* dst = (mode == 0) ? Qb : Kb;
        const int ld = (mode == 0) ? NH * HD : KVDIM;
#pragma unroll
        for (int i = 0; i < 4; ++i)
#pragma unroll
            for (int j = 0; j < 4; ++j) {
                int row = m0 + wr * 64 + i * 16 + q4 * 4;
                int col = nc + wc * 64 + j * 16 + n16;
#pragma unroll
                for (int r = 0; r < 4; ++r)
                    dst[(size_t)(row + r) * ld + col] = (bf16_t)(acc[i][j][r] * osc);
            }
    } else {
        // ---- V: store transposed, 4 consecutive rows per lane contiguous ----
#pragma unroll
        for (int i = 0; i < 4; ++i)
#pragma unroll
            for (int j = 0; j < 4; ++j) {
                int row = m0 + wr * 64 + i * 16 + q4 * 4;
                int col = nc + wc * 64 + j * 16 + n16;
#pragma unroll
                for (int r = 0; r < 4; ++r)
                    Vt[(size_t)col * SEQ + row + r] = (bf16_t)acc[i][j][r];
            }
    }
}

// ---------------------------------------------------------------------------
// O projection: out[SEQ][HID] fp32 = Ob[SEQ][HID](bf16) * Wob[HID][HID]^T(bf16)
// ---------------------------------------------------------------------------
__global__ __launch_bounds__(256) void o_gemm(const bf16_t* __restrict__ A,
                                              const bf16_t* __restrict__ Bw,
                                              float* __restrict__ C)
{
    const int m0 = blockIdx.x * 128;
    const int n0 = blockIdx.y * 128;

    GEMM128_PROLOG()
    GEMM128_KLOOP(A + (size_t)m0 * HID, Bw + (size_t)n0 * HID, HID)

#pragma unroll
    for (int i = 0; i < 4; ++i)
#pragma unroll
        for (int j = 0; j < 4; ++j) {
            int row = m0 + wr * 64 + i * 16 + q4 * 4;
            int col = n0 + wc * 64 + j * 16 + n16;
#pragma unroll
            for (int r = 0; r < 4; ++r)
                C[(size_t)(row + r) * HID + col] = acc[i][j][r];
        }
}

// ---------------------------------------------------------------------------
// MFMA causal flash attention, v2.
// Grid: 1D, heads fastest, heaviest q-tiles first. Bq=64/block (16 rows/wave),
// kv staged 128 at a time via global_load_lds (width=16) into unpadded
// 32-elem-pitch LDS halves (same addressing as the validated GEMM core).
// Two 64-kv compute halves per barrier pair. Causal mask applied only on the
// diagonal half (wave-uniform branch). Q arrives pre-scaled by 1/8.
// ---------------------------------------------------------------------------
__global__ __launch_bounds__(256) void attn_mfma(const bf16_t* __restrict__ Qm,
                                                 const bf16_t* __restrict__ Km,
                                                 const bf16_t* __restrict__ Vt,
                                                 bf16_t* __restrict__ Om)
{
    const int h   = blockIdx.x & (NH - 1);
    const int qt  = (SEQ / 64 - 1) - (blockIdx.x >> 5);   // heavy first
    const int q0  = qt * 64;
    const int kvh = h >> 2;            // H/KVH = 4
    const int t   = threadIdx.x;
    const int w   = t >> 6;
    const int lane = t & 63;
    const int n16 = lane & 15;
    const int q4  = lane >> 4;

    // K: 128 rows x 64 d, split into d-halves (pitch 32)
    __shared__ alignas(16) bf16_t kA[128 * 32];
    __shared__ alignas(16) bf16_t kB[128 * 32];
    // V (transposed): 64 d-rows x 128 c, split into 4 c-chunks of 32 (pitch 32)
    __shared__ alignas(16) bf16_t vA0[64 * 32], vB0[64 * 32];
    __shared__ alignas(16) bf16_t vA1[64 * 32], vB1[64 * 32];
    // per-wave P scratch: 16 m-rows x 64 c, split into c-halves (pitch 32)
    __shared__ alignas(16) bf16_t psA[4][16 * 32];
    __shared__ alignas(16) bf16_t psB[4][16 * 32];

    // persistent Q fragments (A-layout); Qb pre-scaled by 1/8
    const int qrow = q0 + w * 16 + n16;
    const bf16_t* qbase = Qm + (size_t)qrow * HID + h * HD;
    const bf16x8 qf0 = *(const bf16x8*)(qbase + q4 * 8);
    const bf16x8 qf1 = *(const bf16x8*)(qbase + 32 + q4 * 8);

    f32x4 acc[4] = {};
    float m_i[4], l_i[4];
#pragma unroll
    for (int r = 0; r < 4; ++r) { m_i[r] = -1e30f; l_i[r] = 0.0f; }

    // staging lane geometry: lane l -> row (l>>2), 8-elem chunk (l&3)*8
    const int srow = lane >> 2;
    const int scol = (lane & 3) * 8;
    const bf16_t* kg = Km + (size_t)kvh * HD + scol;       // + row*KVDIM
    const bf16_t* vg = Vt + (size_t)(kvh * HD) * SEQ;      // + d*SEQ + c

    const int rowg0 = q0 + w * 16 + q4 * 4;
    const int nhalf = qt + 1;                               // 64-kv halves

    for (int kb = 0; kb * 2 < nhalf; ++kb) {
        const int k0 = kb * 128;
        // ---- stage K (128x64) and V (64x128) via global_load_lds ----
        {
            const int r0 = w * 16 + srow;
            const bf16_t* kp0 = kg + (size_t)(k0 + r0) * KVDIM;
            const bf16_t* kp1 = kg + (size_t)(k0 + 64 + r0) * KVDIM;
            load_lds16(kp0,      &kA[(w * 16) * 32]);
            load_lds16(kp0 + 32, &kB[(w * 16) * 32]);
            load_lds16(kp1,      &kA[(64 + w * 16) * 32]);
            load_lds16(kp1 + 32, &kB[(64 + w * 16) * 32]);
            const bf16_t* vp = vg + (size_t)r0 * SEQ + k0 + scol - scol + scol; // d=r0
            vp = vg + (size_t)r0 * SEQ + k0 + scol;
            load_lds16(vp,      &vA0[(w * 16) * 32]);
            load_lds16(vp + 32, &vB0[(w * 16) * 32]);
            load_lds16(vp + 64, &vA1[(w * 16) * 32]);
            load_lds16(vp + 96, &vB1[(w * 16) * 32]);
        }
        __syncthreads();

#pragma unroll
        for (int hh = 0; hh < 2; ++hh) {
            const int gh = kb * 2 + hh;
            if (gh >= nhalf) break;                        // wave-uniform (qt block-uniform)
            const bf16_t* kAh = &kA[hh * 64 * 32];
            const bf16_t* kBh = &kB[hh * 64 * 32];
            const bf16_t* vAh = hh ? vA1 : vA0;
            const bf16_t* vBh = hh ? vB1 : vB0;

            // ---- S = (Q/8) K^T ----
            f32x4 st[4];
#pragma unroll
            for (int jt = 0; jt < 4; ++jt) {
                bf16x8 kf0 = *(const bf16x8*)&kAh[(jt * 16 + n16) * 32 + q4 * 8];
                bf16x8 kf1 = *(const bf16x8*)&kBh[(jt * 16 + n16) * 32 + q4 * 8];
                f32x4 s = {};
                s = __builtin_amdgcn_mfma_f32_16x16x32_bf16(qf0, kf0, s, 0, 0, 0);
                s = __builtin_amdgcn_mfma_f32_16x16x32_bf16(qf1, kf1, s, 0, 0, 0);
                st[jt] = s;
            }

            // ---- causal mask: diagonal half only ----
            if (gh == qt) {
#pragma unroll
                for (int jt = 0; jt < 4; ++jt) {
                    int colg = gh * 64 + jt * 16 + n16;
#pragma unroll
                    for (int r = 0; r < 4; ++r)
                        if (colg > rowg0 + r) st[jt][r] = -1e30f;
                }
            }

            // ---- online softmax ----
            float rmax[4];
#pragma unroll
            for (int r = 0; r < 4; ++r)
                rmax[r] = fmaxf(fmaxf(st[0][r], st[1][r]), fmaxf(st[2][r], st[3][r]));
#pragma unroll
            for (int msk = 1; msk < 16; msk <<= 1)
#pragma unroll
                for (int r = 0; r < 4; ++r)
                    rmax[r] = fmaxf(rmax[r], __shfl_xor(rmax[r], msk));

            float alpha[4];
#pragma unroll
            for (int r = 0; r < 4; ++r) {
                float mn = fmaxf(m_i[r], rmax[r]);
                alpha[r] = __expf(m_i[r] - mn);
                m_i[r] = mn;
            }

            float rsum[4] = {0.f, 0.f, 0.f, 0.f};
#pragma unroll
            for (int jt = 0; jt < 4; ++jt)
#pragma unroll
                for (int r = 0; r < 4; ++r) {
                    float p = __expf(st[jt][r] - m_i[r]);
                    st[jt][r] = p;
                    rsum[r] += p;
                }
#pragma unroll
            for (int msk = 1; msk < 16; msk <<= 1)
#pragma unroll
                for (int r = 0; r < 4; ++r)
                    rsum[r] += __shfl_xor(rsum[r], msk);

#pragma unroll
            for (int r = 0; r < 4; ++r)
                l_i[r] = l_i[r] * alpha[r] + rsum[r];
#pragma unroll
            for (int jd = 0; jd < 4; ++jd)
#pragma unroll
                for (int r = 0; r < 4; ++r)
                    acc[jd][r] *= alpha[r];

            // ---- P: C-layout regs -> per-wave LDS (bf16, A-layout source) ----
#pragma unroll
            for (int jt = 0; jt < 4; ++jt) {
                bf16_t* ph = (jt < 2) ? psA[w] : psB[w];
                int c16 = (jt & 1) * 16;
#pragma unroll
                for (int r = 0; r < 4; ++r)
                    ph[(q4 * 4 + r) * 32 + c16 + n16] = (bf16_t)st[jt][r];
            }
            // same-wave RAW: compiler-inserted lgkmcnt (m120-verified pattern)
            bf16x8 pf0 = *(const bf16x8*)&psA[w][n16 * 32 + q4 * 8];
            bf16x8 pf1 = *(const bf16x8*)&psB[w][n16 * 32 + q4 * 8];

            // ---- O += P V ----
#pragma unroll
            for (int jd = 0; jd < 4; ++jd) {
                bf16x8 vf0 = *(const bf16x8*)&vAh[(jd * 16 + n16) * 32 + q4 * 8];
                bf16x8 vf1 = *(const bf16x8*)&vBh[(jd * 16 + n16) * 32 + q4 * 8];
                acc[jd] = __builtin_amdgcn_mfma_f32_16x16x32_bf16(pf0, vf0, acc[jd], 0, 0, 0);
                acc[jd] = __builtin_amdgcn_mfma_f32_16x16x32_bf16(pf1, vf1, acc[jd], 0, 0, 0);
            }
        }
        __syncthreads();   // protect K/V LDS before restaging
    }

    // ---- epilogue: O / l ----
    float linv[4];
#pragma unroll
    for (int r = 0; r < 4; ++r) linv[r] = 1.0f / l_i[r];
#pragma unroll
    for (int jd = 0; jd < 4; ++jd)
#pragma unroll
        for (int r = 0; r < 4; ++r) {
            int rowg = rowg0 + r;
            Om[(size_t)rowg * HID + h * HD + jd * 16 + n16] = (bf16_t)(acc[jd][r] * linv[r]);
        }
}

// ---------------------------------------------------------------------------
extern "C" void kernel_launch(void* const* d_in, const int* in_sizes, int n_in,
                              void* d_out, int out_size, void* d_ws, size_t ws_size,
                              hipStream_t stream)
{
    const float* X  = (const float*)d_in[0];
    const float* Wq = (const float*)d_in[1];
    const float* Wk = (const float*)d_in[2];
    const float* Wv = (const float*)d_in[3];
    const float* Wo = (const float*)d_in[4];
    float* out = (float*)d_out;

    bf16_t* Xb  = (bf16_t*)d_ws;                      // [SEQ][HID]     8 MB
    bf16_t* Wqb = Xb  + (size_t)NX;                   // [2048][2048]   8 MB
    bf16_t* Wkb = Wqb + (size_t)NWQ;                  // [512][2048]    2 MB
    bf16_t* Wvb = Wkb + (size_t)NWK;                  // [512][2048]    2 MB
    bf16_t* Wob = Wvb + (size_t)NWV;                  // [2048][2048]   8 MB
    bf16_t* Qb  = Wob + (size_t)NWO;                  // [SEQ][NH*HD]   8 MB (pre-scaled 1/8)
    bf16_t* Kb  = Qb  + (size_t)SEQ * (NH * HD);      // [SEQ][KVDIM]   2 MB
    bf16_t* Vt  = Kb  + (size_t)SEQ * KVDIM;          // [KVDIM][SEQ]   2 MB
    bf16_t* Ob  = Vt  + (size_t)SEQ * KVDIM;          // [SEQ][NH*HD]   8 MB

    dim3 blk(256);

    // one-shot fp32 -> bf16 conversion of all operands
    cvt_all<<<dim3((NTOT / 8 + 255) / 256), blk, 0, stream>>>(X, Wq, Wk, Wv, Wo, Xb, Wqb, Wkb, Wvb, Wob);

    // fused QKV projection + RoPE (Q pre-scaled, V transposed)
    qkv_gemm<<<dim3(SEQ / 128, (NH * HD + 2 * KVDIM) / 128), blk, 0, stream>>>(Xb, Wqb, Wkb, Wvb, Qb, Kb, Vt);

    // causal GQA attention (MFMA flash v2, heavy-first ordering)
    attn_mfma<<<dim3((SEQ / 64) * NH), blk, 0, stream>>>(Qb, Kb, Vt, Ob);

    // output projection -> d_out
    o_gemm<<<dim3(SEQ / 128, HID / 128), blk, 0, stream>>>(Ob, Wob, out);
}